// Round 13
// baseline (410.170 us; speedup 1.0000x reference)
//
#include <hip/hip_runtime.h>
#include <math.h>

#define NN 8192
#define FF 256
#define MAXN 128            // max degree incl. self-loop; Binomial(8191,0.004) max ~60
#define NGEMM ((NN / 64) * (FF / 64))   // 512 gemm tiles; grid = NGEMM+NN = 17*NGEMM

// ---------------------------------------------------------------------------
// K1: heterogeneous blocks, gemm tiles INTERLEAVED 1:16 into the scan stream
// so gemm ALU work hides under the BW-bound adjacency scan.
//   blockIdx % 17 == 0 -> gemm tile (Xp = X@W^T + b, plus fused partial
//                         a_src/a_dst dot products via atomicAdd)
//   else               -> scan one adj row -> compacted neighbor indices
// ---------------------------------------------------------------------------
__global__ __launch_bounds__(256) void gemm_scan_dots_kernel(const float* __restrict__ X,
                                                             const float* __restrict__ W,
                                                             const float* __restrict__ bias,
                                                             const float* __restrict__ S,
                                                             const float* __restrict__ adj,
                                                             float* __restrict__ Xp,
                                                             float* __restrict__ a_src,
                                                             float* __restrict__ a_dst,
                                                             int* __restrict__ cnt_g,
                                                             int* __restrict__ nbr_g) {
    __shared__ float Xs[64][64];
    __shared__ float Ws[64][64];
    const int tid = threadIdx.x;
    const int bid = blockIdx.x;
    const int q17 = bid / 17;

    if (bid % 17 == 0) {
        // ---------------- GEMM path (tile q17 in [0, NGEMM)) ----------------
        const int rt   = q17 >> 2;         // 0..127 row tile
        const int ct   = q17 & 3;          // 0..3   col tile
        const int row0 = rt * 64;
        const int col0 = ct * 64;
        const int ty   = tid >> 4;         // 4 output rows each
        const int tx   = tid & 15;         // 4 output cols each
        const int lrow = tid & 63;
        const int kq0  = (tid >> 6) * 4;

        const float* Xr = &X[(size_t)(row0 + lrow) * FF];
        const float* Wr = &W[(size_t)(col0 + lrow) * FF];

        float4 px[4], pw[4];
#pragma unroll
        for (int q = 0; q < 4; ++q) {
            px[q] = *reinterpret_cast<const float4*>(&Xr[(kq0 + q) * 4]);
            pw[q] = *reinterpret_cast<const float4*>(&Wr[(kq0 + q) * 4]);
        }

        float acc[4][4] = {};

#pragma unroll
        for (int kt = 0; kt < 4; ++kt) {
#pragma unroll
            for (int q = 0; q < 4; ++q) {
                const int k0 = (kq0 + q) * 4;
                Xs[k0+0][lrow]=px[q].x; Xs[k0+1][lrow]=px[q].y; Xs[k0+2][lrow]=px[q].z; Xs[k0+3][lrow]=px[q].w;
                Ws[k0+0][lrow]=pw[q].x; Ws[k0+1][lrow]=pw[q].y; Ws[k0+2][lrow]=pw[q].z; Ws[k0+3][lrow]=pw[q].w;
            }
            __syncthreads();
            if (kt < 3) {
                const int kb = (kt + 1) * 64;
#pragma unroll
                for (int q = 0; q < 4; ++q) {
                    px[q] = *reinterpret_cast<const float4*>(&Xr[kb + (kq0 + q) * 4]);
                    pw[q] = *reinterpret_cast<const float4*>(&Wr[kb + (kq0 + q) * 4]);
                }
            }
#pragma unroll 8
            for (int k = 0; k < 64; ++k) {
                const float4 a4 = *reinterpret_cast<const float4*>(&Xs[k][ty * 4]);
                const float4 b4 = *reinterpret_cast<const float4*>(&Ws[k][tx * 4]);
                const float av[4] = {a4.x, a4.y, a4.z, a4.w};
                const float bv[4] = {b4.x, b4.y, b4.z, b4.w};
#pragma unroll
                for (int ii = 0; ii < 4; ++ii)
#pragma unroll
                    for (int jj = 0; jj < 4; ++jj)
                        acc[ii][jj] = fmaf(av[ii], bv[jj], acc[ii][jj]);
            }
            __syncthreads();
        }

        const float4 b4  = *reinterpret_cast<const float4*>(&bias[col0 + tx * 4]);
        const float4 s0v = *reinterpret_cast<const float4*>(&S[col0 + tx * 4]);
        const float4 s1v = *reinterpret_cast<const float4*>(&S[FF + col0 + tx * 4]);
#pragma unroll
        for (int ii = 0; ii < 4; ++ii) {
            const int r = row0 + ty * 4 + ii;
            float4 o;
            o.x = acc[ii][0] + b4.x;
            o.y = acc[ii][1] + b4.y;
            o.z = acc[ii][2] + b4.z;
            o.w = acc[ii][3] + b4.w;
            *reinterpret_cast<float4*>(&Xp[(size_t)r * FF + col0 + tx * 4]) = o;

            // fused dots: partial over this block's 64 cols, reduced across the
            // 16 tx-lanes of the ty-group (lanes ty*16..ty*16+15, shfl_xor<16)
            float ps = o.x * s0v.x + o.y * s0v.y + o.z * s0v.z + o.w * s0v.w;
            float pd = o.x * s1v.x + o.y * s1v.y + o.z * s1v.z + o.w * s1v.w;
#pragma unroll
            for (int off = 8; off; off >>= 1) {
                ps += __shfl_xor(ps, off);
                pd += __shfl_xor(pd, off);
            }
            if (tx == 0) {
                atomicAdd(&a_src[r], ps);
                atomicAdd(&a_dst[r], pd);
            }
        }
    } else {
        // ---------------- adjacency scan path ----------------
        __shared__ int nbr_s[MAXN];
        __shared__ int cnt;
        const int i = bid - q17 - 1;       // scan row in [0, NN)
        if (tid == 0) cnt = 0;
        __syncthreads();

        const size_t base = (size_t)i * NN;
        float4 v[8];
#pragma unroll
        for (int it = 0; it < 8; ++it)     // all 8 loads in flight (8 KB/wave)
            v[it] = *reinterpret_cast<const float4*>(&adj[base + it * 1024 + tid * 4]);
#pragma unroll
        for (int it = 0; it < 8; ++it) {
            const int c0 = it * 1024 + tid * 4;
            const float vv[4] = {v[it].x, v[it].y, v[it].z, v[it].w};
#pragma unroll
            for (int u = 0; u < 4; ++u) {
                const int col = c0 + u;
                if (vv[u] != 0.f || col == i) {   // (adj!=0 | eye): one mask, no dedupe
                    const int slot = atomicAdd(&cnt, 1);
                    if (slot < MAXN) nbr_s[slot] = col;
                }
            }
        }
        __syncthreads();
        const int n = min(cnt, MAXN);
        if (tid < n) nbr_g[(size_t)i * MAXN + tid] = nbr_s[tid];
        if (tid == 0) cnt_g[i] = n;
    }
}

// ---------------------------------------------------------------------------
// K2: per row i (wave per row, 4 rows/block): softmax over
// leaky_relu(a_src[i]+a_dst[j]) for the compacted neighbor set, then
// out[i,:] = sigmoid( sum_j attn_j * Xp[j,:] ), float4 per lane.
// ---------------------------------------------------------------------------
__global__ __launch_bounds__(256) void agg_kernel(const int* __restrict__ cnt_g,
                                                  const int* __restrict__ nbr_g,
                                                  const float* __restrict__ a_src,
                                                  const float* __restrict__ a_dst,
                                                  const float* __restrict__ Xp,
                                                  float* __restrict__ out) {
    __shared__ int   nb[4][MAXN];
    __shared__ float wt[4][MAXN];

    const int wid  = threadIdx.x >> 6;
    const int lane = threadIdx.x & 63;
    const int i    = blockIdx.x * 4 + wid;

    const int   n  = cnt_g[i];
    const float si = a_src[i];

    int   j0 = 0, j1 = 0;
    float e0 = -INFINITY, e1 = -INFINITY;
    if (lane < n) {
        j0 = nbr_g[(size_t)i * MAXN + lane];
        const float x = si + a_dst[j0];
        e0 = (x >= 0.f) ? x : 0.01f * x;     // jax leaky_relu default slope
    }
    if (lane + 64 < n) {
        j1 = nbr_g[(size_t)i * MAXN + lane + 64];
        const float x = si + a_dst[j1];
        e1 = (x >= 0.f) ? x : 0.01f * x;
    }

    float m = fmaxf(e0, e1);
#pragma unroll
    for (int off = 32; off; off >>= 1) m = fmaxf(m, __shfl_xor(m, off));

    const float w0 = (lane < n)      ? __expf(e0 - m) : 0.f;
    const float w1 = (lane + 64 < n) ? __expf(e1 - m) : 0.f;
    float s = w0 + w1;
#pragma unroll
    for (int off = 32; off; off >>= 1) s += __shfl_xor(s, off);
    const float inv_den = 1.f / s;

    nb[wid][lane]      = j0;
    wt[wid][lane]      = w0 * inv_den;
    nb[wid][lane + 64] = j1;
    wt[wid][lane + 64] = w1 * inv_den;
    // wave-synchronous LDS publish within one 64-lane wave: no barrier needed

    const float* xb = Xp + lane * 4;          // lane owns features [4*lane, 4*lane+4)
    float4 acc = {0.f, 0.f, 0.f, 0.f};
    int k = 0;
    for (; k + 2 <= n; k += 2) {
        const int   g0 = nb[wid][k],  g1 = nb[wid][k + 1];
        const float u0 = wt[wid][k],  u1 = wt[wid][k + 1];
        const float4 v0 = *reinterpret_cast<const float4*>(&xb[(size_t)g0 * FF]);
        const float4 v1 = *reinterpret_cast<const float4*>(&xb[(size_t)g1 * FF]);
        acc.x += u0 * v0.x + u1 * v1.x;
        acc.y += u0 * v0.y + u1 * v1.y;
        acc.z += u0 * v0.z + u1 * v1.z;
        acc.w += u0 * v0.w + u1 * v1.w;
    }
    if (k < n) {
        const int   g0 = nb[wid][k];
        const float u0 = wt[wid][k];
        const float4 v0 = *reinterpret_cast<const float4*>(&xb[(size_t)g0 * FF]);
        acc.x += u0 * v0.x; acc.y += u0 * v0.y; acc.z += u0 * v0.z; acc.w += u0 * v0.w;
    }

    float4 o;
    o.x = 1.f / (1.f + __expf(-acc.x));
    o.y = 1.f / (1.f + __expf(-acc.y));
    o.z = 1.f / (1.f + __expf(-acc.z));
    o.w = 1.f / (1.f + __expf(-acc.w));
    *reinterpret_cast<float4*>(&out[(size_t)i * FF + lane * 4]) = o;
}

// ---------------------------------------------------------------------------
extern "C" void kernel_launch(void* const* d_in, const int* in_sizes, int n_in,
                              void* d_out, int out_size, void* d_ws, size_t ws_size,
                              hipStream_t stream) {
    const float* X   = (const float*)d_in[0];
    const float* adj = (const float*)d_in[1];
    const float* W   = (const float*)d_in[2];
    const float* b   = (const float*)d_in[3];
    const float* S   = (const float*)d_in[4];
    float* out = (float*)d_out;

    float* Xp    = (float*)d_ws;                        // 8 MB
    float* a_src = Xp + (size_t)NN * FF;                // 32 KB (atomic targets,
    float* a_dst = a_src + NN;                          //  zeroed below)
    int*   cnt_g = (int*)(a_dst + NN);                  // 32 KB
    int*   nbr_g = cnt_g + NN;                          // 4 MB

    hipMemsetAsync(a_src, 0, 2 * NN * sizeof(float), stream);  // zero atomic targets
    gemm_scan_dots_kernel<<<NGEMM + NN, 256, 0, stream>>>(X, W, b, S, adj, Xp,
                                                          a_src, a_dst, cnt_g, nbr_g);
    agg_kernel<<<NN / 4, 256, 0, stream>>>(cnt_g, nbr_g, a_src, a_dst, Xp, out);
}

// Round 14
// 398.635 us; speedup vs baseline: 1.0289x; 1.0289x over previous
//
#include <hip/hip_runtime.h>
#include <math.h>

#define NN 8192
#define FF 256
#define MAXN 128            // max degree incl. self-loop; Binomial(8191,0.004) max ~60
#define NGEMM ((NN / 64) * (FF / 64))   // 512 gemm blocks, front-loaded

// ---------------------------------------------------------------------------
// K1: heterogeneous blocks, gemm FRONT-LOADED (R13 showed interleave hurts).
//   blocks [0, NGEMM)        : Xp = X@W^T + b, plus fused a_src/a_dst partial
//                              dot products (shfl-reduced, atomicAdd)
//   blocks [NGEMM, NGEMM+NN) : scan adj row -> compacted neighbor indices
// ---------------------------------------------------------------------------
__global__ __launch_bounds__(256) void gemm_scan_dots_kernel(const float* __restrict__ X,
                                                             const float* __restrict__ W,
                                                             const float* __restrict__ bias,
                                                             const float* __restrict__ S,
                                                             const float* __restrict__ adj,
                                                             float* __restrict__ Xp,
                                                             float* __restrict__ a_src,
                                                             float* __restrict__ a_dst,
                                                             int* __restrict__ cnt_g,
                                                             int* __restrict__ nbr_g) {
    __shared__ float Xs[64][64];
    __shared__ float Ws[64][64];
    const int tid = threadIdx.x;

    if (blockIdx.x < NGEMM) {
        // ---------------- GEMM path ----------------
        const int rt   = blockIdx.x >> 2;   // 0..127 row tile
        const int ct   = blockIdx.x & 3;    // 0..3   col tile
        const int row0 = rt * 64;
        const int col0 = ct * 64;
        const int ty   = tid >> 4;          // 4 output rows each
        const int tx   = tid & 15;          // 4 output cols each
        const int lrow = tid & 63;
        const int kq0  = (tid >> 6) * 4;

        const float* Xr = &X[(size_t)(row0 + lrow) * FF];
        const float* Wr = &W[(size_t)(col0 + lrow) * FF];

        float4 px[4], pw[4];
#pragma unroll
        for (int q = 0; q < 4; ++q) {
            px[q] = *reinterpret_cast<const float4*>(&Xr[(kq0 + q) * 4]);
            pw[q] = *reinterpret_cast<const float4*>(&Wr[(kq0 + q) * 4]);
        }

        float acc[4][4] = {};

#pragma unroll
        for (int kt = 0; kt < 4; ++kt) {
#pragma unroll
            for (int q = 0; q < 4; ++q) {
                const int k0 = (kq0 + q) * 4;
                Xs[k0+0][lrow]=px[q].x; Xs[k0+1][lrow]=px[q].y; Xs[k0+2][lrow]=px[q].z; Xs[k0+3][lrow]=px[q].w;
                Ws[k0+0][lrow]=pw[q].x; Ws[k0+1][lrow]=pw[q].y; Ws[k0+2][lrow]=pw[q].z; Ws[k0+3][lrow]=pw[q].w;
            }
            __syncthreads();
            if (kt < 3) {
                const int kb = (kt + 1) * 64;
#pragma unroll
                for (int q = 0; q < 4; ++q) {
                    px[q] = *reinterpret_cast<const float4*>(&Xr[kb + (kq0 + q) * 4]);
                    pw[q] = *reinterpret_cast<const float4*>(&Wr[kb + (kq0 + q) * 4]);
                }
            }
#pragma unroll 8
            for (int k = 0; k < 64; ++k) {
                const float4 a4 = *reinterpret_cast<const float4*>(&Xs[k][ty * 4]);
                const float4 b4 = *reinterpret_cast<const float4*>(&Ws[k][tx * 4]);
                const float av[4] = {a4.x, a4.y, a4.z, a4.w};
                const float bv[4] = {b4.x, b4.y, b4.z, b4.w};
#pragma unroll
                for (int ii = 0; ii < 4; ++ii)
#pragma unroll
                    for (int jj = 0; jj < 4; ++jj)
                        acc[ii][jj] = fmaf(av[ii], bv[jj], acc[ii][jj]);
            }
            __syncthreads();
        }

        const float4 b4  = *reinterpret_cast<const float4*>(&bias[col0 + tx * 4]);
        const float4 s0v = *reinterpret_cast<const float4*>(&S[col0 + tx * 4]);
        const float4 s1v = *reinterpret_cast<const float4*>(&S[FF + col0 + tx * 4]);
#pragma unroll
        for (int ii = 0; ii < 4; ++ii) {
            const int r = row0 + ty * 4 + ii;
            float4 o;
            o.x = acc[ii][0] + b4.x;
            o.y = acc[ii][1] + b4.y;
            o.z = acc[ii][2] + b4.z;
            o.w = acc[ii][3] + b4.w;
            *reinterpret_cast<float4*>(&Xp[(size_t)r * FF + col0 + tx * 4]) = o;

            // fused dots: partial over this block's 64 cols, reduced across the
            // 16 tx-lanes of the ty-group (shfl_xor width 16 within the wave)
            float ps = o.x * s0v.x + o.y * s0v.y + o.z * s0v.z + o.w * s0v.w;
            float pd = o.x * s1v.x + o.y * s1v.y + o.z * s1v.z + o.w * s1v.w;
#pragma unroll
            for (int off = 8; off; off >>= 1) {
                ps += __shfl_xor(ps, off);
                pd += __shfl_xor(pd, off);
            }
            if (tx == 0) {
                atomicAdd(&a_src[r], ps);
                atomicAdd(&a_dst[r], pd);
            }
        }
    } else {
        // ---------------- adjacency scan path ----------------
        __shared__ int nbr_s[MAXN];
        __shared__ int cnt;
        const int i = blockIdx.x - NGEMM;
        if (tid == 0) cnt = 0;
        __syncthreads();

        const size_t base = (size_t)i * NN;
        float4 v[8];
#pragma unroll
        for (int it = 0; it < 8; ++it)      // all 8 loads in flight (8 KB/wave)
            v[it] = *reinterpret_cast<const float4*>(&adj[base + it * 1024 + tid * 4]);
#pragma unroll
        for (int it = 0; it < 8; ++it) {
            const int c0 = it * 1024 + tid * 4;
            const float vv[4] = {v[it].x, v[it].y, v[it].z, v[it].w};
#pragma unroll
            for (int u = 0; u < 4; ++u) {
                const int col = c0 + u;
                if (vv[u] != 0.f || col == i) {   // (adj!=0 | eye): one mask, no dedupe
                    const int slot = atomicAdd(&cnt, 1);
                    if (slot < MAXN) nbr_s[slot] = col;
                }
            }
        }
        __syncthreads();
        const int n = min(cnt, MAXN);
        if (tid < n) nbr_g[(size_t)i * MAXN + tid] = nbr_s[tid];
        if (tid == 0) cnt_g[i] = n;
    }
}

// ---------------------------------------------------------------------------
// K2: per row i (wave per row, 4 rows/block): softmax over
// leaky_relu(a_src[i]+a_dst[j]) for the compacted neighbor set, then
// out[i,:] = sigmoid( sum_j attn_j * Xp[j,:] ), float4 per lane.
// ---------------------------------------------------------------------------
__global__ __launch_bounds__(256) void agg_kernel(const int* __restrict__ cnt_g,
                                                  const int* __restrict__ nbr_g,
                                                  const float* __restrict__ a_src,
                                                  const float* __restrict__ a_dst,
                                                  const float* __restrict__ Xp,
                                                  float* __restrict__ out) {
    __shared__ int   nb[4][MAXN];
    __shared__ float wt[4][MAXN];

    const int wid  = threadIdx.x >> 6;
    const int lane = threadIdx.x & 63;
    const int i    = blockIdx.x * 4 + wid;

    const int   n  = cnt_g[i];
    const float si = a_src[i];

    int   j0 = 0, j1 = 0;
    float e0 = -INFINITY, e1 = -INFINITY;
    if (lane < n) {
        j0 = nbr_g[(size_t)i * MAXN + lane];
        const float x = si + a_dst[j0];
        e0 = (x >= 0.f) ? x : 0.01f * x;     // jax leaky_relu default slope
    }
    if (lane + 64 < n) {
        j1 = nbr_g[(size_t)i * MAXN + lane + 64];
        const float x = si + a_dst[j1];
        e1 = (x >= 0.f) ? x : 0.01f * x;
    }

    float m = fmaxf(e0, e1);
#pragma unroll
    for (int off = 32; off; off >>= 1) m = fmaxf(m, __shfl_xor(m, off));

    const float w0 = (lane < n)      ? __expf(e0 - m) : 0.f;
    const float w1 = (lane + 64 < n) ? __expf(e1 - m) : 0.f;
    float s = w0 + w1;
#pragma unroll
    for (int off = 32; off; off >>= 1) s += __shfl_xor(s, off);
    const float inv_den = 1.f / s;

    nb[wid][lane]      = j0;
    wt[wid][lane]      = w0 * inv_den;
    nb[wid][lane + 64] = j1;
    wt[wid][lane + 64] = w1 * inv_den;
    // wave-synchronous LDS publish within one 64-lane wave: no barrier needed

    const float* xb = Xp + lane * 4;          // lane owns features [4*lane, 4*lane+4)
    float4 acc = {0.f, 0.f, 0.f, 0.f};
    int k = 0;
    for (; k + 2 <= n; k += 2) {
        const int   g0 = nb[wid][k],  g1 = nb[wid][k + 1];
        const float u0 = wt[wid][k],  u1 = wt[wid][k + 1];
        const float4 v0 = *reinterpret_cast<const float4*>(&xb[(size_t)g0 * FF]);
        const float4 v1 = *reinterpret_cast<const float4*>(&xb[(size_t)g1 * FF]);
        acc.x += u0 * v0.x + u1 * v1.x;
        acc.y += u0 * v0.y + u1 * v1.y;
        acc.z += u0 * v0.z + u1 * v1.z;
        acc.w += u0 * v0.w + u1 * v1.w;
    }
    if (k < n) {
        const int   g0 = nb[wid][k];
        const float u0 = wt[wid][k];
        const float4 v0 = *reinterpret_cast<const float4*>(&xb[(size_t)g0 * FF]);
        acc.x += u0 * v0.x; acc.y += u0 * v0.y; acc.z += u0 * v0.z; acc.w += u0 * v0.w;
    }

    float4 o;
    o.x = 1.f / (1.f + __expf(-acc.x));
    o.y = 1.f / (1.f + __expf(-acc.y));
    o.z = 1.f / (1.f + __expf(-acc.z));
    o.w = 1.f / (1.f + __expf(-acc.w));
    *reinterpret_cast<float4*>(&out[(size_t)i * FF + lane * 4]) = o;
}

// ---------------------------------------------------------------------------
extern "C" void kernel_launch(void* const* d_in, const int* in_sizes, int n_in,
                              void* d_out, int out_size, void* d_ws, size_t ws_size,
                              hipStream_t stream) {
    const float* X   = (const float*)d_in[0];
    const float* adj = (const float*)d_in[1];
    const float* W   = (const float*)d_in[2];
    const float* b   = (const float*)d_in[3];
    const float* S   = (const float*)d_in[4];
    float* out = (float*)d_out;

    float* Xp    = (float*)d_ws;                        // 8 MB
    float* a_src = Xp + (size_t)NN * FF;                // 32 KB (atomic targets,
    float* a_dst = a_src + NN;                          //  zeroed below)
    int*   cnt_g = (int*)(a_dst + NN);                  // 32 KB
    int*   nbr_g = cnt_g + NN;                          // 4 MB

    hipMemsetAsync(a_src, 0, 2 * NN * sizeof(float), stream);  // zero atomic targets
    gemm_scan_dots_kernel<<<NGEMM + NN, 256, 0, stream>>>(X, W, b, S, adj, Xp,
                                                          a_src, a_dst, cnt_g, nbr_g);
    agg_kernel<<<NN / 4, 256, 0, stream>>>(cnt_g, nbr_g, a_src, a_dst, Xp, out);
}